// Round 8
// baseline (451.906 us; speedup 1.0000x reference)
//
#include <hip/hip_runtime.h>
#include <math.h>

#define BB 2
#define SS 2048
#define DD 2048
#define HH 16
#define DN 128
#define DR 64
#define DV 128
#define QL 1536
#define KVL 512
#define DQ 192           // DN + DR
#define CKVS 640         // ckv row stride (576 padded to 640)
#define KVD 256          // DN + DV
#define NCAT 2176        // QL + CKVS (fused first GEMM)
#define NCATP 2304       // NCAT padded to 9*256 for the 256-wide GEMM tile
#define EPSF 1e-6f

typedef short bfrag __attribute__((ext_vector_type(8)));   // 8 bf16 (4 VGPRs)
typedef float facc  __attribute__((ext_vector_type(4)));   // 4 fp32 acc

// ---------------- helpers ----------------
__device__ __forceinline__ ushort f2bf(float f) {
    union { float f; unsigned u; } v; v.f = f;
    unsigned r = v.u + 0x7fffu + ((v.u >> 16) & 1u);  // RNE
    return (ushort)(r >> 16);
}
__device__ __forceinline__ float bf2f(ushort u) {
    union { unsigned u; float f; } v; v.u = ((unsigned)u) << 16;
    return v.f;
}
__device__ __forceinline__ float fexp2(float x) {   // raw v_exp_f32 (2^x)
    float r; asm("v_exp_f32 %0, %1" : "=v"(r) : "v"(x)); return r;
}
__device__ __forceinline__ float wave_red_sum(float v) {
    #pragma unroll
    for (int o = 32; o > 0; o >>= 1) v += __shfl_down(v, o);
    return v;
}
__device__ __forceinline__ void gl2lds16(const ushort* g, ushort* l) {
    __builtin_amdgcn_global_load_lds(
        (const __attribute__((address_space(1))) void*)g,
        (__attribute__((address_space(3))) void*)l, 16, 0, 0);
}

// ---------------- fp32 -> bf16 cast (vectorized) ----------------
__global__ __launch_bounds__(256) void castf2bf(const float* __restrict__ x,
                                                ushort* __restrict__ y) {
    const int i = blockIdx.x * 256 + threadIdx.x;
    const float4 v = ((const float4*)x)[i];
    ushort4 o;
    o.x = f2bf(v.x); o.y = f2bf(v.y); o.z = f2bf(v.z); o.w = f2bf(v.w);
    ((ushort4*)y)[i] = o;
}

// ------- batched weight cast+transpose (now only Wqa, Wkva) ----------
struct WtBatch {
    const float* src[2];
    ushort* dst[2];
    int K[2];
    int N[2];
    int nx[2];
    int base[3];
};
__global__ __launch_bounds__(256) void wtrans_b(WtBatch d) {
    __shared__ float tile[32][33];
    int bid = blockIdx.x;
    int seg = (bid >= d.base[1]) ? 1 : 0;
    const int l = bid - d.base[seg];
    const int nx = d.nx[seg];
    const int bx = l % nx, by = l / nx;
    const float* W = d.src[seg];
    ushort* Wt = d.dst[seg];
    const int K = d.K[seg], N = d.N[seg];
    const int k0 = by * 32, n0 = bx * 32;
    const int t = threadIdx.x;
    const int tx = t & 31, ty = t >> 5;
    #pragma unroll
    for (int r = 0; r < 4; ++r) {
        const int n = n0 + tx;
        tile[ty + r * 8][tx] =
            (n < N) ? W[(size_t)(k0 + ty + r * 8) * N + n] : 0.f;
    }
    __syncthreads();
    #pragma unroll
    for (int r = 0; r < 4; ++r) {
        const int n = n0 + ty + r * 8;
        Wt[(size_t)n * K + k0 + tx] = f2bf(tile[tx][ty + r * 8]);
    }
}

// ================== 256x256 8-phase MFMA GEMM core (m201 template) =========
// Caller declares __shared__ ushort L[65536] and passes pre-swizzled LID_.

__device__ __forceinline__ void stage_half(const ushort* __restrict__ G,
                                           int ldg, int grow0, int kcol0,
                                           ushort* Lr, int wave, int lane) {
    const int r0   = lane >> 3;
    const int slot = (lane & 7) ^ r0;          // inverse-swizzled global slot
    const ushort* s0 = G + (size_t)(grow0 + wave * 16 + r0) * ldg + kcol0 + slot * 8;
    gl2lds16(s0,                    Lr + wave * 1024);        // rows w*16..+8
    gl2lds16(s0 + (size_t)8 * ldg,  Lr + wave * 1024 + 512);  // rows +8..+16
}

#define PH_PRE  do { __builtin_amdgcn_sched_barrier(0);                      \
                     __builtin_amdgcn_s_barrier();                           \
                     asm volatile("s_waitcnt lgkmcnt(0)" ::: "memory");      \
                     __builtin_amdgcn_sched_barrier(0);                      \
                     __builtin_amdgcn_s_setprio(1); } while (0)
#define PH_POST do { __builtin_amdgcn_s_setprio(0);                          \
                     __builtin_amdgcn_sched_barrier(0);                      \
                     __builtin_amdgcn_s_barrier(); } while (0)

#define MFMA16(RB)                                                           \
    _Pragma("unroll")                                                        \
    for (int i = 0; i < 4; ++i)                                              \
        _Pragma("unroll")                                                    \
        for (int j = 0; j < 4; ++j)                                          \
            acc[(RB) + i][j] = __builtin_amdgcn_mfma_f32_16x16x32_bf16(      \
                a[i], b[j], acc[(RB) + i][j], 0, 0, 0);

#define GEMM256_CORE(A_, Bt_, K_, NBX_, LID_)                                 \
    const int t    = threadIdx.x;                                             \
    const int lane = t & 63;                                                  \
    const int wave = t >> 6;                                                  \
    const int wm   = wave >> 2;                                               \
    const int wn   = wave & 3;                                                \
    const int quad = lane >> 4;                                               \
    const int lrow = lane & 15;                                               \
    const int bx = (LID_) % (NBX_), by = (LID_) / (NBX_);                     \
    const int m0 = by * 256, n0 = bx * 256;                                   \
    const int s0x8  = (quad ^ (lrow & 7)) * 8;   /* swizzled slot, kh=0 */    \
    const int s1x8  = s0x8 ^ 32;                 /* kh=1: slot^4          */  \
    const int abase = lrow * 64;                                              \
    const int bbase = (wn & 1) * 4096 + lrow * 64;                            \
    facc acc[8][4];                                                           \
    _Pragma("unroll")                                                         \
    for (int i = 0; i < 8; ++i)                                               \
        _Pragma("unroll")                                                     \
        for (int j = 0; j < 4; ++j) acc[i][j] = (facc)(0.f);                  \
    const int nk = (K_) >> 6;                                                 \
    stage_half((A_),  (K_), m0,        0, L,         wave, lane);             \
    stage_half((A_),  (K_), m0 + 128,  0, L + 8192,  wave, lane);             \
    stage_half((Bt_), (K_), n0,        0, L + 16384, wave, lane);             \
    stage_half((Bt_), (K_), n0 + 128,  0, L + 24576, wave, lane);             \
    stage_half((Bt_), (K_), n0,       64, L + 49152, wave, lane);             \
    stage_half((Bt_), (K_), n0 + 128, 64, L + 57344, wave, lane);             \
    asm volatile("s_waitcnt vmcnt(4)" ::: "memory");                          \
    __builtin_amdgcn_s_barrier();                                             \
    for (int kt = 0; kt < nk; ++kt) {                                         \
        const int p = kt & 1;                                                 \
        ushort* LA = L + p * 32768 + wm * 8192;                               \
        ushort* LB = L + p * 32768 + 16384 + (wn >> 1) * 8192;                \
        ushort* Lq = L + (p ^ 1) * 32768;                                     \
        const int kn = (kt + 1) * 64;                                         \
        bfrag a[4], b[4];                                                     \
        _Pragma("unroll")                                                     \
        for (int i = 0; i < 4; ++i)                                           \
            a[i] = *(const bfrag*)(LA + i * 1024 + abase + s0x8);             \
        _Pragma("unroll")                                                     \
        for (int j = 0; j < 4; ++j)                                           \
            b[j] = *(const bfrag*)(LB + bbase + j * 1024 + s0x8);             \
        if (kt + 1 < nk) stage_half((A_), (K_), m0, kn, Lq, wave, lane);      \
        PH_PRE;                                                               \
        MFMA16(0)                                                             \
        PH_POST;                                                              \
        _Pragma("unroll")                                                     \
        for (int i = 0; i < 4; ++i)                                           \
            a[i] = *(const bfrag*)(LA + (4 + i) * 1024 + abase + s0x8);       \
        if (kt + 1 < nk)                                                      \
            stage_half((A_), (K_), m0 + 128, kn, Lq + 8192, wave, lane);      \
        PH_PRE;                                                               \
        MFMA16(4)                                                             \
        PH_POST;                                                              \
        _Pragma("unroll")                                                     \
        for (int i = 0; i < 4; ++i)                                           \
            a[i] = *(const bfrag*)(LA + i * 1024 + abase + s1x8);             \
        _Pragma("unroll")                                                     \
        for (int j = 0; j < 4; ++j)                                           \
            b[j] = *(const bfrag*)(LB + bbase + j * 1024 + s1x8);             \
        PH_PRE;                                                               \
        MFMA16(0)                                                             \
        PH_POST;                                                              \
        _Pragma("unroll")                                                     \
        for (int i = 0; i < 4; ++i)                                           \
            a[i] = *(const bfrag*)(LA + (4 + i) * 1024 + abase + s1x8);       \
        if (kt + 2 < nk) {                                                    \
            stage_half((Bt_), (K_), n0,       kn + 64,                        \
                       L + p * 32768 + 16384, wave, lane);                    \
            stage_half((Bt_), (K_), n0 + 128, kn + 64,                        \
                       L + p * 32768 + 24576, wave, lane);                    \
            asm volatile("s_waitcnt vmcnt(4)" ::: "memory");                  \
        } else {                                                              \
            asm volatile("s_waitcnt vmcnt(0)" ::: "memory");                  \
        }                                                                     \
        PH_PRE;                                                               \
        MFMA16(4)                                                             \
        PH_POST;                                                              \
    }

// ------- gemmO: out = ao @ Wo (fp32), 8-phase 256^2 (r2/r3-verified) -------
__global__ __launch_bounds__(512, 2) void gemmO(const ushort* __restrict__ A,
                                                const ushort* __restrict__ Bt,
                                                float* __restrict__ C) {
    __shared__ ushort L[65536];
    const int bid = (int)blockIdx.x;
    const int lid = (bid & 7) * 16 + (bid >> 3);   // 128 = 16*8 bijective
    GEMM256_CORE(A, Bt, DD, 8, lid)
    #pragma unroll
    for (int m = 0; m < 8; ++m) {
        const int row = m0 + wm * 128 + m * 16 + quad * 4;
        #pragma unroll
        for (int nf = 0; nf < 4; ++nf) {
            const int col = n0 + wn * 64 + nf * 16 + lrow;
            #pragma unroll
            for (int r = 0; r < 4; ++r)
                C[(size_t)(row + r) * DD + col] = acc[m][nf][r];
        }
    }
}

// ====== gemmAW: gemmA (144 x 256^2 blocks) + 112 transpose-walker blocks ====
__global__ __launch_bounds__(512, 2) void gemmAW(
    const ushort* __restrict__ A,   const ushort* __restrict__ Bt,
    ushort* __restrict__ qa,        ushort* __restrict__ ckv,
    const float* __restrict__ Wqb,  ushort* __restrict__ Wqbt,
    const float* __restrict__ Wkvb, ushort* __restrict__ Wkvbt,
    const float* __restrict__ Wo,   ushort* __restrict__ Wot) {
    __shared__ ushort L[65536];
    const int bid = (int)blockIdx.x;
    if (bid < 144) {
        const int lid = (bid & 7) * 18 + (bid >> 3);   // 144 = 18*8 bijective
        GEMM256_CORE(A, Bt, DD, 9, lid)
        #pragma unroll
        for (int m = 0; m < 8; ++m) {
            const int row = m0 + wm * 128 + m * 16 + quad * 4;
            #pragma unroll
            for (int nf = 0; nf < 4; ++nf) {
                const int col = n0 + wn * 64 + nf * 16 + lrow;
                #pragma unroll
                for (int r = 0; r < 4; ++r) {
                    if (col < QL)
                        qa[(size_t)(row + r) * QL + col] = f2bf(acc[m][nf][r]);
                    else if (col < NCAT)
                        ckv[(size_t)(row + r) * CKVS + col - QL] = f2bf(acc[m][nf][r]);
                }
            }
        }
    } else {
        const int wid = bid - 144;            // 0..111
        const int t   = threadIdx.x;
        const int half = t >> 8;              // two 256-thread halves
        const int tl = t & 255;
        const int tx = tl & 31, ty = tl >> 5;
        float (*tile)[33] = (float(*)[33])((float*)L + half * 32 * 33);
        for (int it = 0; it < 48; ++it) {
            const int idx = (it * 112 + wid) * 2 + half;   // 0..10751
            const float* W; ushort* Wt; int K, N, nx, l;
            if (idx < 4608)      { l = idx;        W = Wqb;  Wt = Wqbt;  K = QL;  N = HH * DQ;  nx = 96; }
            else if (idx < 6656) { l = idx - 4608; W = Wkvb; Wt = Wkvbt; K = KVL; N = HH * KVD; nx = 128; }
            else                 { l = idx - 6656; W = Wo;   Wt = Wot;   K = DD;  N = DD;       nx = 64; }
            const int bx2 = l % nx, by2 = l / nx;
            const int k0 = by2 * 32, n0w = bx2 * 32;
            #pragma unroll
            for (int r = 0; r < 4; ++r)
                tile[ty + r * 8][tx] = W[(size_t)(k0 + ty + r * 8) * N + n0w + tx];
            __syncthreads();
            #pragma unroll
            for (int r = 0; r < 4; ++r)
                Wt[(size_t)(n0w + ty + r * 8) * K + k0 + tx] = f2bf(tile[tx][ty + r * 8]);
            __syncthreads();
        }
    }
}

// ------ grouped GEMM (8-phase 256^2): blocks 0..191 = Q, 192..447 = kv ------
__global__ __launch_bounds__(512, 2) void gemmQKV(
    const ushort* __restrict__ qa,  const ushort* __restrict__ Wqbt,
    ushort* __restrict__ Qbuf,
    const ushort* __restrict__ kvn, const ushort* __restrict__ Wkvbt,
    ushort* __restrict__ kvb) {
    __shared__ ushort L[65536];
    const int bid = (int)blockIdx.x;
    if (bid < 192) {
        const int lid = (bid & 7) * 24 + (bid >> 3);       // 192 = 24*8
        GEMM256_CORE(qa, Wqbt, QL, 12, lid)
        const float scaling = 0.10411754831f; // 192^-0.5 * log2(e)
        #pragma unroll
        for (int m = 0; m < 8; ++m) {
            const int row = m0 + wm * 128 + m * 16 + quad * 4;
            #pragma unroll
            for (int nf = 0; nf < 4; ++nf) {
                const int col = n0 + wn * 64 + nf * 16 + lrow;
                const int h = col / DQ, d = col - h * DQ;
                #pragma unroll
                for (int r = 0; r < 4; ++r) {
                    const int tok = row + r;
                    const int b = tok >> 11, s2 = tok & (SS - 1);
                    Qbuf[((size_t)(b * HH + h) * SS + s2) * DQ + d] =
                        f2bf(acc[m][nf][r] * scaling);
                }
            }
        }
    } else {
        const int b2 = bid - 192;
        const int lid = (b2 & 7) * 32 + (b2 >> 3);         // 256 = 32*8
        GEMM256_CORE(kvn, Wkvbt, KVL, 16, lid)
        #pragma unroll
        for (int m = 0; m < 8; ++m) {
            const int row = m0 + wm * 128 + m * 16 + quad * 4;
            #pragma unroll
            for (int nf = 0; nf < 4; ++nf) {
                const int col = n0 + wn * 64 + nf * 16 + lrow;
                #pragma unroll
                for (int r = 0; r < 4; ++r)
                    kvb[(size_t)(row + r) * (HH * KVD) + col] = f2bf(acc[m][nf][r]);
            }
        }
    }
}

// ------- merged RMSNorms: bid<T -> qa in-place; else kv norm + k_rot rope ---
__global__ __launch_bounds__(256) void rmsnorm2(ushort* __restrict__ qa,
                                                const float* __restrict__ qaw,
                                                const ushort* __restrict__ ckv,
                                                const float* __restrict__ kvw,
                                                ushort* __restrict__ kvn,
                                                ushort* __restrict__ krb,
                                                const float* __restrict__ cosb,
                                                const float* __restrict__ sinb) {
    __shared__ float red[4];
    const int t = threadIdx.x;
    const int lane = t & 63, wid = t >> 6;
    const int bid = (int)blockIdx.x;
    if (bid < BB * SS) {
        ushort* xr = qa + (size_t)bid * QL;
        float ss = 0.f;
        for (int i = t; i < QL; i += 256) { float v = bf2f(xr[i]); ss += v * v; }
        ss = wave_red_sum(ss);
        if (lane == 0) red[wid] = ss;
        __syncthreads();
        const float tot = red[0] + red[1] + red[2] + red[3];
        const float sc = rsqrtf(tot / (float)QL + EPSF);
        for (int i = t; i < QL; i += 256) xr[i] = f2bf(qaw[i] * bf2f(xr[i]) * sc);
    } else {
        const int row = bid - BB * SS;
        const ushort* xr = ckv + (size_t)row * CKVS;
        ushort* yr = kvn + (size_t)row * KVL;
        if (t < 64) {   // k_rot rope (independent of the norm)
            const int p = t;
            const ushort* kin = xr + KVL;
            const float c  = cosb[(size_t)row * DR + p];
            const float sn = sinb[(size_t)row * DR + p];
            const float self = bf2f(kin[p]);
            const float partner = bf2f(kin[p < 32 ? p + 32 : p - 32]);
            const float v = (p < 32) ? (self * c - partner * sn)
                                     : (self * c + partner * sn);
            krb[(size_t)row * DR + p] = f2bf(v);
        }
        float ss = 0.f;
        for (int i = t; i < KVL; i += 256) { float v = bf2f(xr[i]); ss += v * v; }
        ss = wave_red_sum(ss);
        if (lane == 0) red[wid] = ss;
        __syncthreads();
        const float tot = red[0] + red[1] + red[2] + red[3];
        const float sc = rsqrtf(tot / (float)KVL + EPSF);
        for (int i = t; i < KVL; i += 256) yr[i] = f2bf(kvw[i] * bf2f(xr[i]) * sc);
    }
}

// ------- merged qrope + vprep: bid<T -> rope Qbuf; else V-transpose --------
__global__ __launch_bounds__(256) void ropevprep(ushort* __restrict__ Qbuf,
                                                 const float* __restrict__ cosb,
                                                 const float* __restrict__ sinb,
                                                 const ushort* __restrict__ kvb,
                                                 ushort* __restrict__ Vtb) {
    __shared__ ushort tile[32][33];
    const int bid = (int)blockIdx.x;
    const int t = threadIdx.x;
    if (bid < BB * SS) {
        const int tok = bid;
        const int b = tok >> 11, s = tok & (SS - 1);
        const int p = t & 31, hh = t >> 5;
        const float c0 = cosb[(size_t)tok * DR + p];
        const float s0 = sinb[(size_t)tok * DR + p];
        const float c1 = cosb[(size_t)tok * DR + p + 32];
        const float s1 = sinb[(size_t)tok * DR + p + 32];
        #pragma unroll
        for (int it = 0; it < 2; ++it) {
            const int h = hh + it * 8;
            ushort* base = Qbuf + ((size_t)(b * HH + h) * SS + s) * DQ + DN;
            const float x0 = bf2f(base[p]), x1 = bf2f(base[p + 32]);
            base[p]      = f2bf(x0 * c0 - x1 * s0);
            base[p + 32] = f2bf(x1 * c1 + x0 * s1);
        }
    } else {
        const int v = bid - BB * SS;             // 0..8191
        const int kp0 = (v & 63) * 32;
        const int dv0 = ((v >> 6) & 3) * 32;
        const int bh  = v >> 8;
        const int b = bh / HH, h = bh - b * HH;
        const int tx = t & 31, ty = t >> 5;
        #pragma unroll
        for (int r = 0; r < 4; ++r)
            tile[ty + r * 8][tx] =
                kvb[(size_t)(b * SS + kp0 + ty + r * 8) * (HH * KVD) + h * KVD + DN + dv0 + tx];
        __syncthreads();
        #pragma unroll
        for (int r = 0; r < 4; ++r)
            Vtb[((size_t)bh * DV + dv0 + ty + r * 8) * SS + kp0 + tx] = tile[tx][ty + r * 8];
    }
}

// ---------------- MFMA flash attention, 8-wave blocks (v5) ----------------
// v5: 512 threads = 8 waves, each owning ONE 16-row strip of the 128-row
// q-tile (the old 2-strip sp dimension is deleted).  LDS unchanged (60KB,
// 2 blocks/CU) -> waves/SIMD 2->4: doubles the independent streams hiding
// the QK^T->softmax->PV serial chain (r7 analysis: MFMA ~14K of 204K cyc,
// no pipe near ceiling -> TLP-bound).  Staging regrouped to 8 waves
// (3 K-groups + 2 V-groups per wave); prefetch regs halve (kreg[3],vreg[2]).
__global__ __launch_bounds__(512, 4) void fattn_mfma(
    const ushort* __restrict__ Qb,   // [(b*HH+h)*SS+s][192] pre-scaled+roped
    const ushort* __restrict__ kvb,  // [tok][HH*KVD]
    const ushort* __restrict__ krb,  // [tok][64]
    const ushort* __restrict__ Vt,   // [(b*HH+h)*DV+dv][SS]
    ushort* __restrict__ o)          // [tok][HH*DV]
{
    const int h  = blockIdx.y;
    const int b  = blockIdx.z;
    const int qt = b ? (15 - (int)blockIdx.x) : (int)blockIdx.x;
    const int bh = b * HH + h;
    const int q0 = qt * 128;
    const int t    = threadIdx.x;
    const int lane = t & 63;
    const int wave = t >> 6;          // 0..7
    const int quad = lane >> 4;
    const int n    = lane & 15;
    const int wstrip = wave * 16;     // each wave owns rows wstrip..wstrip+15

    __shared__ ushort Ksu[6 * 64 * 32];   // 24 KB
    __shared__ ushort Vtu[2 * 128 * 32];  // 16 KB
    __shared__ ushort Psu[2 * 128 * 40];  // 20 KB (padded rows)

    const ushort* vbase = Vt + (size_t)bh * DV * SS;

    // preload Q A-frags (one strip per wave)
    bfrag aQ[6];
    {
        const ushort* qrow = Qb + ((size_t)bh * SS + q0 + wstrip + n) * DQ;
        #pragma unroll
        for (int kb = 0; kb < 6; ++kb)
            aQ[kb] = *(const bfrag*)(qrow + kb * 32 + quad * 8);
    }

    facc oacc[8];
    float lp[4];
    #pragma unroll
    for (int jd = 0; jd < 8; ++jd) oacc[jd] = (facc)(0.f);
    #pragma unroll
    for (int r = 0; r < 4; ++r) lp[r] = 0.f;

    // prologue: stage tile kt=0 via global_load_lds (8-wave grouping)
    #pragma unroll
    for (int i = 0; i < 3; ++i) {
        const int g = wave + 8 * i;               // 0..23
        const int kb = g >> 2;                    // wave-uniform
        const int rem = (g & 3) * 64 + lane;
        const int row = rem >> 2, sub = rem & 3;
        const int tok = b * SS + row;
        const ushort* src = (kb < 4)
            ? kvb + (size_t)tok * (HH * KVD) + h * KVD + kb * 32 + sub * 8
            : krb + (size_t)tok * DR + (kb - 4) * 32 + sub * 8;
        gl2lds16(src, Ksu + g * 512);
    }
    #pragma unroll
    for (int i = 0; i < 2; ++i) {
        const int g = wave + 8 * i;               // 0..15
        const int kb2 = g >> 3;                   // wave-uniform
        const int rem = (g & 7) * 64 + lane;
        const int dv = rem >> 2, sub = rem & 3;
        gl2lds16(vbase + (size_t)dv * SS + kb2 * 32 + sub * 8, Vtu + g * 512);
    }
    __syncthreads();

    const int nkt = 2 * qt + 2;
    for (int kt = 0; kt < nkt; ++kt) {
        const int k0 = kt * 64;
        const int kk = (kt + 1 < nkt) ? (k0 + 64) : (SS - 64);  // clamped

        // ---- issue next-tile global loads into registers (UNCONDITIONAL) ---
        bfrag kreg[3], vreg[2];
        #pragma unroll
        for (int i = 0; i < 3; ++i) {
            const int g = wave + 8 * i;
            const int kb = g >> 2;
            const int rem = (g & 3) * 64 + lane;
            const int row = rem >> 2, sub = rem & 3;
            const int tok = b * SS + kk + row;
            const ushort* src = (kb < 4)
                ? kvb + (size_t)tok * (HH * KVD) + h * KVD + kb * 32 + sub * 8
                : krb + (size_t)tok * DR + (kb - 4) * 32 + sub * 8;
            kreg[i] = *(const bfrag*)src;
        }
        #pragma unroll
        for (int i = 0; i < 2; ++i) {
            const int g = wave + 8 * i;
            const int kb2 = g >> 3;
            const int rem = (g & 7) * 64 + lane;
            const int dv = rem >> 2, sub = rem & 3;
            vreg[i] = *(const bfrag*)(vbase + (size_t)dv * SS + kk + kb2 * 32 + sub * 8);
        }
        __builtin_amdgcn_sched_barrier(0);   // pin load issue BEFORE compute

        // ---- S = Q K^T (one strip) ----
        facc s[4];
        #pragma unroll
        for (int j = 0; j < 4; ++j) s[j] = (facc)(0.f);
        #pragma unroll
        for (int kb = 0; kb < 6; ++kb) {
            #pragma unroll
            for (int j = 0; j < 4; ++j) {
                const bfrag bk =
                    *(const bfrag*)&Ksu[kb * 2048 + (j * 16 + n) * 32 + quad * 8];
                s[j] = __builtin_amdgcn_mfma_f32_16x16x32_bf16(aQ[kb], bk, s[j], 0, 0, 0);
            }
        }

        // ---- exp2 (m=0) + causal select; P -> LDS (wave-private rows) ----
        const bool fullt = (k0 + 64 <= q0);   // tile entirely below diagonal
        if (fullt) {
            #pragma unroll
            for (int j = 0; j < 4; ++j) {
                #pragma unroll
                for (int r = 0; r < 4; ++r) {
                    const float p = fexp2(s[j][r]);
                    lp[r] += p;
                    Psu[(j >> 1) * 5120 + (wstrip + quad * 4 + r) * 40
                        + (j & 1) * 16 + n] = f2bf(p);
                }
            }
        } else {
            const int rowg0 = q0 + wstrip + quad * 4;
            #pragma unroll
            for (int j = 0; j < 4; ++j) {
                const int kpos = k0 + j * 16 + n;
                #pragma unroll
                for (int r = 0; r < 4; ++r) {
                    const float p = (kpos <= rowg0 + r) ? fexp2(s[j][r]) : 0.f;
                    lp[r] += p;
                    Psu[(j >> 1) * 5120 + (wstrip + quad * 4 + r) * 40
                        + (j & 1) * 16 + n] = f2bf(p);
                }
            }
        }

        // ---- O += P @ V ----
        #pragma unroll
        for (int kb2 = 0; kb2 < 2; ++kb2) {
            const bfrag aP = *(const bfrag*)&Psu[kb2 * 5120 + (wstrip + n) * 40 + quad * 8];
            #pragma unroll
            for (int jd = 0; jd < 8; ++jd) {
                const bfrag bV = *(const bfrag*)&Vtu[kb2 * 4096 + (jd * 16 + n) * 32 + quad * 8];
                oacc[jd] = __builtin_amdgcn_mfma_f32_16x16x32_bf16(aP, bV, oacc[jd], 0, 0, 0);
            }
        }

        __syncthreads();   // LDS readers drained (+ drains vmcnt -> regs valid)
        // refill Ksu/Vtu from registers (UNCONDITIONAL; dead on last iter)
        #pragma unroll
        for (int i = 0; i < 3; ++i)
            *(bfrag*)(Ksu + (wave + 8 * i) * 512 + lane * 8) = kreg[i];
        #pragma unroll
        for (int i = 0; i < 2; ++i)
            *(bfrag*)(Vtu + (wave + 8 * i) * 512 + lane * 8) = vreg[i];
        __syncthreads();   // new tile visible before next QK^T
    }

    // reduce l partials, epilogue
    #pragma unroll
    for (int r = 0; r < 4; ++r) {
        float v = lp[r];
        #pragma unroll
        for (int msk = 1; msk < 16; msk <<= 1) v += __shfl_xor(v, msk);
        const float inv = 1.f / v;
        ushort* op = o + (size_t)(b * SS + q0 + wstrip + quad * 4 + r)
                         * (HH * DV) + h * DV;
        #pragma unroll
        for (int jd = 0; jd < 8; ++jd)
            op[jd * 16 + n] = f2bf(oacc[jd][r] * inv);
    }
}

// ---------------- launch ----------------
extern "C" void kernel_launch(void* const* d_in, const int* in_sizes, int n_in,
                              void* d_out, int out_size, void* d_ws, size_t ws_size,
                              hipStream_t stream) {
    const float* hs    = (const float*)d_in[0];
    const float* cosb  = (const float*)d_in[1];
    const float* sinb  = (const float*)d_in[2];
    const float* Wqa   = (const float*)d_in[3];
    const float* qa_w  = (const float*)d_in[4];
    const float* Wqb   = (const float*)d_in[5];
    const float* Wkva  = (const float*)d_in[6];
    const float* kva_w = (const float*)d_in[7];
    const float* Wkvb  = (const float*)d_in[8];
    const float* Wo    = (const float*)d_in[9];
    float* out = (float*)d_out;

    const int T = BB * SS; // 4096 tokens

    char* w = (char*)d_ws;
    auto alloc = [&](size_t bytes) {
        void* r = (void*)w;
        w += (bytes + 255) & ~(size_t)255;
        return r;
    };
    ushort* hs_bf  = (ushort*)alloc((size_t)T * DD * 2);            // 16.8 MB
    ushort* Wcat   = (ushort*)alloc((size_t)NCATP * DD * 2);        //  9.4
    ushort* Wqbt   = (ushort*)alloc((size_t)(HH * DQ) * QL * 2);    //  9.4
    ushort* Wkvbt  = (ushort*)alloc((size_t)(HH * KVD) * KVL * 2);  //  4.2
    ushort* Wot    = (ushort*)alloc((size_t)DD * DD * 2);           //  8.4
    ushort* qa_bf  = (ushort*)alloc((size_t)T * QL * 2);            // 12.6
    ushort* Qbuf   = (ushort*)alloc((size_t)T * HH * DQ * 2);       // 25.2
    ushort* ckv_bf = (ushort*)alloc((size_t)T * CKVS * 2);          //  5.2
    ushort* kvn_bf = (ushort*)alloc((size_t)T * KVL * 2);           //  4.2
    ushort* kv_bf  = (ushort*)alloc((size_t)T * HH * KVD * 2);      // 33.6
    ushort* krb    = (ushort*)alloc((size_t)T * DR * 2);            //  0.5
    // aliases (lifetimes verified):
    ushort* Vtb    = Wcat;   // over Wcat+Wqbt (dead after gemmAW/gemmQKV)
    ushort* ao_bf  = hs_bf;  // hs_bf dead after gemmAW

    // 0. cast hs; transpose Wqa/Wkva only (the rest backfills gemmAW)
    castf2bf<<<(T * DD / 4) / 256, 256, 0, stream>>>(hs, hs_bf);
    WtBatch wb;
    wb.src[0] = Wqa;  wb.dst[0] = Wcat;                   wb.K[0] = DD; wb.N[0] = QL;       wb.nx[0] = 48;
    wb.src[1] = Wkva; wb.dst[1] = Wcat + (size_t)QL * DD; wb.K[1] = DD; wb.N[1] = KVL + DR; wb.nx[1] = 20;
    wb.base[0] = 0;
    wb.base[1] = wb.nx[0] * (DD / 32);                // 3072
    wb.base[2] = wb.base[1] + wb.nx[1] * (DD / 32);   // 4352
    wtrans_b<<<wb.base[2], 256, 0, stream>>>(wb);

    // 1. gemmA (144 blocks) + Wqb/Wkvb/Wo transpose walkers (112 blocks)
    gemmAW<<<dim3(256), 512, 0, stream>>>(hs_bf, Wcat, qa_bf, ckv_bf,
                                          Wqb, Wqbt, Wkvb, Wkvbt, Wo, Wot);
    // 2. both RMSNorms (qa in-place; ckv->kvn + k_rot rope) in ONE launch
    rmsnorm2<<<2 * T, 256, 0, stream>>>(qa_bf, qa_w, ckv_bf, kva_w, kvn_bf,
                                        krb, cosb, sinb);
    // 3. grouped GEMM (8-phase 256^2): Q (192 blocks) + kv (256 blocks)
    gemmQKV<<<dim3(448), 512, 0, stream>>>(qa_bf, Wqbt, Qbuf,
                                           kvn_bf, Wkvbt, kv_bf);
    // 4. rope Q + V transpose in ONE launch
    ropevprep<<<T + 8192, 256, 0, stream>>>(Qbuf, cosb, sinb, kv_bf, Vtb);
    // 5. MFMA flash attention (8-wave blocks) -> ao (bf16)
    fattn_mfma<<<dim3(16, HH, BB), 512, 0, stream>>>(Qbuf, kv_bf, krb, Vtb, ao_bf);
    // 6. out = ao @ Wo (fp32), 8-phase 256^2, 128 blocks
    gemmO<<<dim3(128), 512, 0, stream>>>(ao_bf, Wot, out);
}

// Round 9
// 403.997 us; speedup vs baseline: 1.1186x; 1.1186x over previous
//
#include <hip/hip_runtime.h>
#include <math.h>

#define BB 2
#define SS 2048
#define DD 2048
#define HH 16
#define DN 128
#define DR 64
#define DV 128
#define QL 1536
#define KVL 512
#define DQ 192           // DN + DR
#define CKVS 640         // ckv row stride (576 padded to 640)
#define KVD 256          // DN + DV
#define NCAT 2176        // QL + CKVS (fused first GEMM)
#define NCATP 2304       // NCAT padded to 9*256 for the 256-wide GEMM tile
#define EPSF 1e-6f

typedef short bfrag __attribute__((ext_vector_type(8)));   // 8 bf16 (4 VGPRs)
typedef float facc  __attribute__((ext_vector_type(4)));   // 4 fp32 acc

// ---------------- helpers ----------------
__device__ __forceinline__ ushort f2bf(float f) {
    union { float f; unsigned u; } v; v.f = f;
    unsigned r = v.u + 0x7fffu + ((v.u >> 16) & 1u);  // RNE
    return (ushort)(r >> 16);
}
__device__ __forceinline__ float bf2f(ushort u) {
    union { unsigned u; float f; } v; v.u = ((unsigned)u) << 16;
    return v.f;
}
__device__ __forceinline__ float fexp2(float x) {   // raw v_exp_f32 (2^x)
    float r; asm("v_exp_f32 %0, %1" : "=v"(r) : "v"(x)); return r;
}
__device__ __forceinline__ float wave_red_sum(float v) {
    #pragma unroll
    for (int o = 32; o > 0; o >>= 1) v += __shfl_down(v, o);
    return v;
}
__device__ __forceinline__ void gl2lds16(const ushort* g, ushort* l) {
    __builtin_amdgcn_global_load_lds(
        (const __attribute__((address_space(1))) void*)g,
        (__attribute__((address_space(3))) void*)l, 16, 0, 0);
}

// ------- merged cast + weight-transpose (Wqa/Wkva): one producer launch -----
struct WtBatch {
    const float* src[2];
    ushort* dst[2];
    int K[2];
    int N[2];
    int nx[2];
    int base[3];
};
__global__ __launch_bounds__(256) void castw(const float* __restrict__ x,
                                             ushort* __restrict__ y,
                                             WtBatch d) {
    __shared__ float tile[32][33];
    const int bid = (int)blockIdx.x;
    const int t = threadIdx.x;
    if (bid < 8192) {            // fp32 -> bf16 cast of hs (vectorized)
        const int i = bid * 256 + t;
        const float4 v = ((const float4*)x)[i];
        ushort4 o;
        o.x = f2bf(v.x); o.y = f2bf(v.y); o.z = f2bf(v.z); o.w = f2bf(v.w);
        ((ushort4*)y)[i] = o;
    } else {                     // Wqa/Wkva cast+transpose
        const int bl = bid - 8192;
        const int seg = (bl >= d.base[1]) ? 1 : 0;
        const int l = bl - d.base[seg];
        const int nx = d.nx[seg];
        const int bx = l % nx, by = l / nx;
        const float* W = d.src[seg];
        ushort* Wt = d.dst[seg];
        const int K = d.K[seg], N = d.N[seg];
        const int k0 = by * 32, n0 = bx * 32;
        const int tx = t & 31, ty = t >> 5;
        #pragma unroll
        for (int r = 0; r < 4; ++r) {
            const int n = n0 + tx;
            tile[ty + r * 8][tx] =
                (n < N) ? W[(size_t)(k0 + ty + r * 8) * N + n] : 0.f;
        }
        __syncthreads();
        #pragma unroll
        for (int r = 0; r < 4; ++r) {
            const int n = n0 + ty + r * 8;
            Wt[(size_t)n * K + k0 + tx] = f2bf(tile[tx][ty + r * 8]);
        }
    }
}

// ================== 256x256 8-phase MFMA GEMM core (m201 template) =========
// Caller declares __shared__ ushort L[65536] and passes pre-swizzled LID_.

__device__ __forceinline__ void stage_half(const ushort* __restrict__ G,
                                           int ldg, int grow0, int kcol0,
                                           ushort* Lr, int wave, int lane) {
    const int r0   = lane >> 3;
    const int slot = (lane & 7) ^ r0;          // inverse-swizzled global slot
    const ushort* s0 = G + (size_t)(grow0 + wave * 16 + r0) * ldg + kcol0 + slot * 8;
    gl2lds16(s0,                    Lr + wave * 1024);        // rows w*16..+8
    gl2lds16(s0 + (size_t)8 * ldg,  Lr + wave * 1024 + 512);  // rows +8..+16
}

#define PH_PRE  do { __builtin_amdgcn_sched_barrier(0);                      \
                     __builtin_amdgcn_s_barrier();                           \
                     asm volatile("s_waitcnt lgkmcnt(0)" ::: "memory");      \
                     __builtin_amdgcn_sched_barrier(0);                      \
                     __builtin_amdgcn_s_setprio(1); } while (0)
#define PH_POST do { __builtin_amdgcn_s_setprio(0);                          \
                     __builtin_amdgcn_sched_barrier(0);                      \
                     __builtin_amdgcn_s_barrier(); } while (0)

#define MFMA16(RB)                                                           \
    _Pragma("unroll")                                                        \
    for (int i = 0; i < 4; ++i)                                              \
        _Pragma("unroll")                                                    \
        for (int j = 0; j < 4; ++j)                                          \
            acc[(RB) + i][j] = __builtin_amdgcn_mfma_f32_16x16x32_bf16(      \
                a[i], b[j], acc[(RB) + i][j], 0, 0, 0);

#define GEMM256_CORE(A_, Bt_, K_, NBX_, LID_)                                 \
    const int t    = threadIdx.x;                                             \
    const int lane = t & 63;                                                  \
    const int wave = t >> 6;                                                  \
    const int wm   = wave >> 2;                                               \
    const int wn   = wave & 3;                                                \
    const int quad = lane >> 4;                                               \
    const int lrow = lane & 15;                                               \
    const int bx = (LID_) % (NBX_), by = (LID_) / (NBX_);                     \
    const int m0 = by * 256, n0 = bx * 256;                                   \
    const int s0x8  = (quad ^ (lrow & 7)) * 8;   /* swizzled slot, kh=0 */    \
    const int s1x8  = s0x8 ^ 32;                 /* kh=1: slot^4          */  \
    const int abase = lrow * 64;                                              \
    const int bbase = (wn & 1) * 4096 + lrow * 64;                            \
    facc acc[8][4];                                                           \
    _Pragma("unroll")                                                         \
    for (int i = 0; i < 8; ++i)                                               \
        _Pragma("unroll")                                                     \
        for (int j = 0; j < 4; ++j) acc[i][j] = (facc)(0.f);                  \
    const int nk = (K_) >> 6;                                                 \
    stage_half((A_),  (K_), m0,        0, L,         wave, lane);             \
    stage_half((A_),  (K_), m0 + 128,  0, L + 8192,  wave, lane);             \
    stage_half((Bt_), (K_), n0,        0, L + 16384, wave, lane);             \
    stage_half((Bt_), (K_), n0 + 128,  0, L + 24576, wave, lane);             \
    stage_half((Bt_), (K_), n0,       64, L + 49152, wave, lane);             \
    stage_half((Bt_), (K_), n0 + 128, 64, L + 57344, wave, lane);             \
    asm volatile("s_waitcnt vmcnt(4)" ::: "memory");                          \
    __builtin_amdgcn_s_barrier();                                             \
    for (int kt = 0; kt < nk; ++kt) {                                         \
        const int p = kt & 1;                                                 \
        ushort* LA = L + p * 32768 + wm * 8192;                               \
        ushort* LB = L + p * 32768 + 16384 + (wn >> 1) * 8192;                \
        ushort* Lq = L + (p ^ 1) * 32768;                                     \
        const int kn = (kt + 1) * 64;                                         \
        bfrag a[4], b[4];                                                     \
        _Pragma("unroll")                                                     \
        for (int i = 0; i < 4; ++i)                                           \
            a[i] = *(const bfrag*)(LA + i * 1024 + abase + s0x8);             \
        _Pragma("unroll")                                                     \
        for (int j = 0; j < 4; ++j)                                           \
            b[j] = *(const bfrag*)(LB + bbase + j * 1024 + s0x8);             \
        if (kt + 1 < nk) stage_half((A_), (K_), m0, kn, Lq, wave, lane);      \
        PH_PRE;                                                               \
        MFMA16(0)                                                             \
        PH_POST;                                                              \
        _Pragma("unroll")                                                     \
        for (int i = 0; i < 4; ++i)                                           \
            a[i] = *(const bfrag*)(LA + (4 + i) * 1024 + abase + s0x8);       \
        if (kt + 1 < nk)                                                      \
            stage_half((A_), (K_), m0 + 128, kn, Lq + 8192, wave, lane);      \
        PH_PRE;                                                               \
        MFMA16(4)                                                             \
        PH_POST;                                                              \
        _Pragma("unroll")                                                     \
        for (int i = 0; i < 4; ++i)                                           \
            a[i] = *(const bfrag*)(LA + i * 1024 + abase + s1x8);             \
        _Pragma("unroll")                                                     \
        for (int j = 0; j < 4; ++j)                                           \
            b[j] = *(const bfrag*)(LB + bbase + j * 1024 + s1x8);             \
        PH_PRE;                                                               \
        MFMA16(0)                                                             \
        PH_POST;                                                              \
        _Pragma("unroll")                                                     \
        for (int i = 0; i < 4; ++i)                                           \
            a[i] = *(const bfrag*)(LA + (4 + i) * 1024 + abase + s1x8);       \
        if (kt + 2 < nk) {                                                    \
            stage_half((Bt_), (K_), n0,       kn + 64,                        \
                       L + p * 32768 + 16384, wave, lane);                    \
            stage_half((Bt_), (K_), n0 + 128, kn + 64,                        \
                       L + p * 32768 + 24576, wave, lane);                    \
            asm volatile("s_waitcnt vmcnt(4)" ::: "memory");                  \
        } else {                                                              \
            asm volatile("s_waitcnt vmcnt(0)" ::: "memory");                  \
        }                                                                     \
        PH_PRE;                                                               \
        MFMA16(4)                                                             \
        PH_POST;                                                              \
    }

// ====== 256x128-tile 2-phase core (full-fill variant; schedule per r4-r7) ===
#define GEMMW_CORE(A_, Bt_, K_, NBX_, LID_)                                   \
    const int t    = threadIdx.x;                                             \
    const int lane = t & 63;                                                  \
    const int wave = t >> 6;                                                  \
    const int wm   = wave >> 1;          /* 0..3 */                           \
    const int wn   = wave & 1;           /* 0..1 */                           \
    const int quad = lane >> 4;                                               \
    const int lrow = lane & 15;                                               \
    const int bx = (LID_) % (NBX_), by = (LID_) / (NBX_);                     \
    const int m0 = by * 256, n0 = bx * 128;                                   \
    const int s0x8 = (quad ^ (lrow & 7)) * 8;                                 \
    const int s1x8 = s0x8 ^ 32;                                               \
    facc acc[4][4];                                                           \
    _Pragma("unroll")                                                         \
    for (int i = 0; i < 4; ++i)                                               \
        _Pragma("unroll")                                                     \
        for (int j = 0; j < 4; ++j) acc[i][j] = (facc)(0.f);                  \
    const int nk = (K_) >> 6;                                                 \
    stage_half((A_),  (K_), m0,        0, L,          wave, lane);            \
    stage_half((A_),  (K_), m0 + 128,  0, L + 8192,   wave, lane);            \
    stage_half((Bt_), (K_), n0,        0, L + 32768,  wave, lane);            \
    stage_half((Bt_), (K_), n0,       64, L + 40960,  wave, lane);            \
    asm volatile("s_waitcnt vmcnt(0)" ::: "memory");                          \
    __builtin_amdgcn_s_barrier();                                             \
    int bp = 0, bp2 = 2;   /* kt%3 and (kt+2)%3 */                            \
    for (int kt = 0; kt < nk; ++kt) {                                         \
        const int p = kt & 1;                                                 \
        ushort* LA = L + p * 16384 + (wm >> 1) * 8192                         \
                       + ((wm & 1) * 64 + lrow) * 64;                         \
        ushort* LB = L + 32768 + bp * 8192 + (wn * 64 + lrow) * 64;           \
        const int kn = (kt + 1) * 64;                                         \
        bfrag a[4], b[4];                                                     \
        _Pragma("unroll")                                                     \
        for (int i = 0; i < 4; ++i) a[i] = *(const bfrag*)(LA + i * 1024 + s0x8); \
        _Pragma("unroll")                                                     \
        for (int j = 0; j < 4; ++j) b[j] = *(const bfrag*)(LB + j * 1024 + s0x8); \
        if (kt + 1 < nk) {                                                    \
            stage_half((A_), (K_), m0,       kn, L + (p ^ 1) * 16384,        wave, lane); \
            stage_half((A_), (K_), m0 + 128, kn, L + (p ^ 1) * 16384 + 8192, wave, lane); \
        }                                                                     \
        if (kt + 2 < nk)                                                      \
            stage_half((Bt_), (K_), n0, kn + 64, L + 32768 + bp2 * 8192, wave, lane); \
        PH_PRE;                                                               \
        MFMA16(0)                                                             \
        PH_POST;                                                              \
        _Pragma("unroll")                                                     \
        for (int i = 0; i < 4; ++i) a[i] = *(const bfrag*)(LA + i * 1024 + s1x8); \
        _Pragma("unroll")                                                     \
        for (int j = 0; j < 4; ++j) b[j] = *(const bfrag*)(LB + j * 1024 + s1x8); \
        if (kt + 2 < nk) { asm volatile("s_waitcnt vmcnt(2)" ::: "memory"); } \
        else             { asm volatile("s_waitcnt vmcnt(0)" ::: "memory"); } \
        PH_PRE;                                                               \
        MFMA16(0)                                                             \
        PH_POST;                                                              \
        bp  = (bp  == 2) ? 0 : bp  + 1;                                       \
        bp2 = (bp2 == 2) ? 0 : bp2 + 1;                                       \
    }

// ------- gemmW: out = ao @ Wo (fp32), 256x128 tiles, full 256-block fill ----
template <int K, int NBX, int NOUT>
__global__ __launch_bounds__(512, 2) void gemmW(const ushort* __restrict__ A,
                                                const ushort* __restrict__ Bt,
                                                float* __restrict__ C) {
    __shared__ ushort L[57344];   // 112 KiB
    int wg = (int)blockIdx.x;
    { const int cpx = (int)gridDim.x >> 3; wg = (wg & 7) * cpx + (wg >> 3); }
    GEMMW_CORE(A, Bt, K, NBX, wg)
    #pragma unroll
    for (int m = 0; m < 4; ++m) {
        const int row = m0 + wm * 64 + m * 16 + quad * 4;
        #pragma unroll
        for (int nf = 0; nf < 4; ++nf) {
            const int col = n0 + wn * 64 + nf * 16 + lrow;
            #pragma unroll
            for (int r = 0; r < 4; ++r)
                C[(size_t)(row + r) * NOUT + col] = acc[m][nf][r];
        }
    }
}

// ====== gemmAW: gemmA (144 x 256^2 blocks) + 112 transpose-walker blocks ====
__global__ __launch_bounds__(512, 2) void gemmAW(
    const ushort* __restrict__ A,   const ushort* __restrict__ Bt,
    ushort* __restrict__ qa,        ushort* __restrict__ ckv,
    const float* __restrict__ Wqb,  ushort* __restrict__ Wqbt,
    const float* __restrict__ Wkvb, ushort* __restrict__ Wkvbt,
    const float* __restrict__ Wo,   ushort* __restrict__ Wot) {
    __shared__ ushort L[65536];
    const int bid = (int)blockIdx.x;
    if (bid < 144) {
        const int lid = (bid & 7) * 18 + (bid >> 3);   // 144 = 18*8 bijective
        GEMM256_CORE(A, Bt, DD, 9, lid)
        #pragma unroll
        for (int m = 0; m < 8; ++m) {
            const int row = m0 + wm * 128 + m * 16 + quad * 4;
            #pragma unroll
            for (int nf = 0; nf < 4; ++nf) {
                const int col = n0 + wn * 64 + nf * 16 + lrow;
                #pragma unroll
                for (int r = 0; r < 4; ++r) {
                    if (col < QL)
                        qa[(size_t)(row + r) * QL + col] = f2bf(acc[m][nf][r]);
                    else if (col < NCAT)
                        ckv[(size_t)(row + r) * CKVS + col - QL] = f2bf(acc[m][nf][r]);
                }
            }
        }
    } else {
        const int wid = bid - 144;            // 0..111
        const int t   = threadIdx.x;
        const int half = t >> 8;              // two 256-thread halves
        const int tl = t & 255;
        const int tx = tl & 31, ty = tl >> 5;
        float (*tile)[33] = (float(*)[33])((float*)L + half * 32 * 33);
        for (int it = 0; it < 48; ++it) {
            const int idx = (it * 112 + wid) * 2 + half;   // 0..10751
            const float* W; ushort* Wt; int K, N, nx, l;
            if (idx < 4608)      { l = idx;        W = Wqb;  Wt = Wqbt;  K = QL;  N = HH * DQ;  nx = 96; }
            else if (idx < 6656) { l = idx - 4608; W = Wkvb; Wt = Wkvbt; K = KVL; N = HH * KVD; nx = 128; }
            else                 { l = idx - 6656; W = Wo;   Wt = Wot;   K = DD;  N = DD;       nx = 64; }
            const int bx2 = l % nx, by2 = l / nx;
            const int k0 = by2 * 32, n0w = bx2 * 32;
            #pragma unroll
            for (int r = 0; r < 4; ++r)
                tile[ty + r * 8][tx] = W[(size_t)(k0 + ty + r * 8) * N + n0w + tx];
            __syncthreads();
            #pragma unroll
            for (int r = 0; r < 4; ++r)
                Wt[(size_t)(n0w + ty + r * 8) * K + k0 + tx] = f2bf(tile[tx][ty + r * 8]);
            __syncthreads();
        }
    }
}

// ------ grouped GEMM (8-phase 256^2): blocks 0..191 = Q, 192..447 = kv ------
__global__ __launch_bounds__(512, 2) void gemmQKV(
    const ushort* __restrict__ qa,  const ushort* __restrict__ Wqbt,
    ushort* __restrict__ Qbuf,
    const ushort* __restrict__ kvn, const ushort* __restrict__ Wkvbt,
    ushort* __restrict__ kvb) {
    __shared__ ushort L[65536];
    const int bid = (int)blockIdx.x;
    if (bid < 192) {
        const int lid = (bid & 7) * 24 + (bid >> 3);       // 192 = 24*8
        GEMM256_CORE(qa, Wqbt, QL, 12, lid)
        const float scaling = 0.10411754831f; // 192^-0.5 * log2(e)
        #pragma unroll
        for (int m = 0; m < 8; ++m) {
            const int row = m0 + wm * 128 + m * 16 + quad * 4;
            #pragma unroll
            for (int nf = 0; nf < 4; ++nf) {
                const int col = n0 + wn * 64 + nf * 16 + lrow;
                const int h = col / DQ, d = col - h * DQ;
                #pragma unroll
                for (int r = 0; r < 4; ++r) {
                    const int tok = row + r;
                    const int b = tok >> 11, s2 = tok & (SS - 1);
                    Qbuf[((size_t)(b * HH + h) * SS + s2) * DQ + d] =
                        f2bf(acc[m][nf][r] * scaling);
                }
            }
        }
    } else {
        const int b2 = bid - 192;
        const int lid = (b2 & 7) * 32 + (b2 >> 3);         // 256 = 32*8
        GEMM256_CORE(kvn, Wkvbt, KVL, 16, lid)
        #pragma unroll
        for (int m = 0; m < 8; ++m) {
            const int row = m0 + wm * 128 + m * 16 + quad * 4;
            #pragma unroll
            for (int nf = 0; nf < 4; ++nf) {
                const int col = n0 + wn * 64 + nf * 16 + lrow;
                #pragma unroll
                for (int r = 0; r < 4; ++r)
                    kvb[(size_t)(row + r) * (HH * KVD) + col] = f2bf(acc[m][nf][r]);
            }
        }
    }
}

// ------- merged RMSNorms: bid<T -> qa in-place; else kv norm + k_rot rope ---
__global__ __launch_bounds__(256) void rmsnorm2(ushort* __restrict__ qa,
                                                const float* __restrict__ qaw,
                                                const ushort* __restrict__ ckv,
                                                const float* __restrict__ kvw,
                                                ushort* __restrict__ kvn,
                                                ushort* __restrict__ krb,
                                                const float* __restrict__ cosb,
                                                const float* __restrict__ sinb) {
    __shared__ float red[4];
    const int t = threadIdx.x;
    const int lane = t & 63, wid = t >> 6;
    const int bid = (int)blockIdx.x;
    if (bid < BB * SS) {
        ushort* xr = qa + (size_t)bid * QL;
        float ss = 0.f;
        for (int i = t; i < QL; i += 256) { float v = bf2f(xr[i]); ss += v * v; }
        ss = wave_red_sum(ss);
        if (lane == 0) red[wid] = ss;
        __syncthreads();
        const float tot = red[0] + red[1] + red[2] + red[3];
        const float sc = rsqrtf(tot / (float)QL + EPSF);
        for (int i = t; i < QL; i += 256) xr[i] = f2bf(qaw[i] * bf2f(xr[i]) * sc);
    } else {
        const int row = bid - BB * SS;
        const ushort* xr = ckv + (size_t)row * CKVS;
        ushort* yr = kvn + (size_t)row * KVL;
        if (t < 64) {   // k_rot rope (independent of the norm)
            const int p = t;
            const ushort* kin = xr + KVL;
            const float c  = cosb[(size_t)row * DR + p];
            const float sn = sinb[(size_t)row * DR + p];
            const float self = bf2f(kin[p]);
            const float partner = bf2f(kin[p < 32 ? p + 32 : p - 32]);
            const float v = (p < 32) ? (self * c - partner * sn)
                                     : (self * c + partner * sn);
            krb[(size_t)row * DR + p] = f2bf(v);
        }
        float ss = 0.f;
        for (int i = t; i < KVL; i += 256) { float v = bf2f(xr[i]); ss += v * v; }
        ss = wave_red_sum(ss);
        if (lane == 0) red[wid] = ss;
        __syncthreads();
        const float tot = red[0] + red[1] + red[2] + red[3];
        const float sc = rsqrtf(tot / (float)KVL + EPSF);
        for (int i = t; i < KVL; i += 256) yr[i] = f2bf(kvw[i] * bf2f(xr[i]) * sc);
    }
}

// ------- merged qrope + vprep: bid<T -> rope Qbuf; else V-transpose --------
__global__ __launch_bounds__(256) void ropevprep(ushort* __restrict__ Qbuf,
                                                 const float* __restrict__ cosb,
                                                 const float* __restrict__ sinb,
                                                 const ushort* __restrict__ kvb,
                                                 ushort* __restrict__ Vtb) {
    __shared__ ushort tile[32][33];
    const int bid = (int)blockIdx.x;
    const int t = threadIdx.x;
    if (bid < BB * SS) {
        const int tok = bid;
        const int b = tok >> 11, s = tok & (SS - 1);
        const int p = t & 31, hh = t >> 5;
        const float c0 = cosb[(size_t)tok * DR + p];
        const float s0 = sinb[(size_t)tok * DR + p];
        const float c1 = cosb[(size_t)tok * DR + p + 32];
        const float s1 = sinb[(size_t)tok * DR + p + 32];
        #pragma unroll
        for (int it = 0; it < 2; ++it) {
            const int h = hh + it * 8;
            ushort* base = Qbuf + ((size_t)(b * HH + h) * SS + s) * DQ + DN;
            const float x0 = bf2f(base[p]), x1 = bf2f(base[p + 32]);
            base[p]      = f2bf(x0 * c0 - x1 * s0);
            base[p + 32] = f2bf(x1 * c1 + x0 * s1);
        }
    } else {
        const int v = bid - BB * SS;             // 0..8191
        const int kp0 = (v & 63) * 32;
        const int dv0 = ((v >> 6) & 3) * 32;
        const int bh  = v >> 8;
        const int b = bh / HH, h = bh - b * HH;
        const int tx = t & 31, ty = t >> 5;
        #pragma unroll
        for (int r = 0; r < 4; ++r)
            tile[ty + r * 8][tx] =
                kvb[(size_t)(b * SS + kp0 + ty + r * 8) * (HH * KVD) + h * KVD + DN + dv0 + tx];
        __syncthreads();
        #pragma unroll
        for (int r = 0; r < 4; ++r)
            Vtb[((size_t)bh * DV + dv0 + ty + r * 8) * SS + kp0 + tx] = tile[tx][ty + r * 8];
    }
}

// ---------------- MFMA flash attention (r7-verified v4, 256 threads) ------
// 4 waves x 2 strips: each K/V LDS fragment read feeds TWO MFMAs (r8 lesson:
// this sharing is load-bearing; 8-wave split doubled LDS traffic and lost 38%).
__global__ __launch_bounds__(256, 2) void fattn_mfma(
    const ushort* __restrict__ Qb,   // [(b*HH+h)*SS+s][192] pre-scaled+roped
    const ushort* __restrict__ kvb,  // [tok][HH*KVD]
    const ushort* __restrict__ krb,  // [tok][64]
    const ushort* __restrict__ Vt,   // [(b*HH+h)*DV+dv][SS]
    ushort* __restrict__ o)          // [tok][HH*DV]
{
    const int h  = blockIdx.y;
    const int b  = blockIdx.z;
    const int qt = b ? (15 - (int)blockIdx.x) : (int)blockIdx.x;
    const int bh = b * HH + h;
    const int q0 = qt * 128;
    const int t    = threadIdx.x;
    const int lane = t & 63;
    const int wave = t >> 6;
    const int quad = lane >> 4;
    const int n    = lane & 15;
    const int wstrip = wave * 16;

    __shared__ ushort Ksu[6 * 64 * 32];   // 24 KB
    __shared__ ushort Vtu[2 * 128 * 32];  // 16 KB
    __shared__ ushort Psu[2 * 128 * 40];  // 20 KB (padded rows)

    const ushort* vbase = Vt + (size_t)bh * DV * SS;

    // preload Q A-frags for both strips
    bfrag aQ[2][6];
    #pragma unroll
    for (int sp = 0; sp < 2; ++sp) {
        const ushort* qrow = Qb + ((size_t)bh * SS + q0 + sp * 64 + wstrip + n) * DQ;
        #pragma unroll
        for (int kb = 0; kb < 6; ++kb)
            aQ[sp][kb] = *(const bfrag*)(qrow + kb * 32 + quad * 8);
    }

    facc oacc[2][8];
    float lp[2][4];
    #pragma unroll
    for (int sp = 0; sp < 2; ++sp) {
        #pragma unroll
        for (int jd = 0; jd < 8; ++jd) oacc[sp][jd] = (facc)(0.f);
        #pragma unroll
        for (int r = 0; r < 4; ++r) lp[sp][r] = 0.f;
    }

    // prologue: stage tile kt=0 via global_load_lds
    #pragma unroll
    for (int i = 0; i < 6; ++i) {
        const int g = wave + 4 * i;
        const int kb = g >> 2;                    // wave-uniform
        const int rem = (g & 3) * 64 + lane;
        const int row = rem >> 2, sub = rem & 3;
        const int tok = b * SS + row;
        const ushort* src = (kb < 4)
            ? kvb + (size_t)tok * (HH * KVD) + h * KVD + kb * 32 + sub * 8
            : krb + (size_t)tok * DR + (kb - 4) * 32 + sub * 8;
        gl2lds16(src, Ksu + g * 512);
    }
    #pragma unroll
    for (int i = 0; i < 4; ++i) {
        const int g = wave + 4 * i;
        const int kb2 = g >> 3;                   // wave-uniform
        const int rem = (g & 7) * 64 + lane;
        const int dv = rem >> 2, sub = rem & 3;
        gl2lds16(vbase + (size_t)dv * SS + kb2 * 32 + sub * 8, Vtu + g * 512);
    }
    __syncthreads();

    const int nkt = 2 * qt + 2;
    for (int kt = 0; kt < nkt; ++kt) {
        const int k0 = kt * 64;
        const int kk = (kt + 1 < nkt) ? (k0 + 64) : (SS - 64);  // clamped

        // ---- issue next-tile global loads into registers (UNCONDITIONAL) ---
        bfrag kreg[6], vreg[4];
        #pragma unroll
        for (int i = 0; i < 6; ++i) {
            const int g = wave + 4 * i;
            const int kb = g >> 2;
            const int rem = (g & 3) * 64 + lane;
            const int row = rem >> 2, sub = rem & 3;
            const int tok = b * SS + kk + row;
            const ushort* src = (kb < 4)
                ? kvb + (size_t)tok * (HH * KVD) + h * KVD + kb * 32 + sub * 8
                : krb + (size_t)tok * DR + (kb - 4) * 32 + sub * 8;
            kreg[i] = *(const bfrag*)src;
        }
        #pragma unroll
        for (int i = 0; i < 4; ++i) {
            const int g = wave + 4 * i;
            const int kb2 = g >> 3;
            const int rem = (g & 7) * 64 + lane;
            const int dv = rem >> 2, sub = rem & 3;
            vreg[i] = *(const bfrag*)(vbase + (size_t)dv * SS + kk + kb2 * 32 + sub * 8);
        }
        __builtin_amdgcn_sched_barrier(0);   // pin load issue BEFORE compute

        // ---- S = Q K^T, both strips share each K frag ----
        facc s[2][4];
        #pragma unroll
        for (int sp = 0; sp < 2; ++sp)
            #pragma unroll
            for (int j = 0; j < 4; ++j) s[sp][j] = (facc)(0.f);
        #pragma unroll
        for (int kb = 0; kb < 6; ++kb) {
            #pragma unroll
            for (int j = 0; j < 4; ++j) {
                const bfrag bk =
                    *(const bfrag*)&Ksu[kb * 2048 + (j * 16 + n) * 32 + quad * 8];
                s[0][j] = __builtin_amdgcn_mfma_f32_16x16x32_bf16(aQ[0][kb], bk, s[0][j], 0, 0, 0);
                s[1][j] = __builtin_amdgcn_mfma_f32_16x16x32_bf16(aQ[1][kb], bk, s[1][j], 0, 0, 0);
            }
        }

        // ---- exp2 (m=0) + causal select; P -> LDS (wave-private rows) ----
        const bool fullt = (k0 + 64 <= q0);   // tile entirely below diagonal
        if (fullt) {
            #pragma unroll
            for (int sp = 0; sp < 2; ++sp) {
                #pragma unroll
                for (int j = 0; j < 4; ++j) {
                    #pragma unroll
                    for (int r = 0; r < 4; ++r) {
                        const float p = fexp2(s[sp][j][r]);
                        lp[sp][r] += p;
                        Psu[(j >> 1) * 5120 + (sp * 64 + wstrip + quad * 4 + r) * 40
                            + (j & 1) * 16 + n] = f2bf(p);
                    }
                }
            }
        } else {
            #pragma unroll
            for (int sp = 0; sp < 2; ++sp) {
                const int rowg0 = q0 + sp * 64 + wstrip + quad * 4;
                #pragma unroll
                for (int j = 0; j < 4; ++j) {
                    const int kpos = k0 + j * 16 + n;
                    #pragma unroll
                    for (int r = 0; r < 4; ++r) {
                        const float p = (kpos <= rowg0 + r) ? fexp2(s[sp][j][r]) : 0.f;
                        lp[sp][r] += p;
                        Psu[(j >> 1) * 5120 + (sp * 64 + wstrip + quad * 4 + r) * 40
                            + (j & 1) * 16 + n] = f2bf(p);
                    }
                }
            }
        }

        // ---- O += P @ V; V frags shared across strips ----
        #pragma unroll
        for (int kb2 = 0; kb2 < 2; ++kb2) {
            const bfrag aP0 = *(const bfrag*)&Psu[kb2 * 5120 + (wstrip + n) * 40 + quad * 8];
            const bfrag aP1 = *(const bfrag*)&Psu[kb2 * 5120 + (64 + wstrip + n) * 40 + quad * 8];
            #pragma unroll
            for (int jd = 0; jd < 8; ++jd) {
                const bfrag bV = *(const bfrag*)&Vtu[kb2 * 4096 + (jd * 16 + n) * 32 + quad * 8];
                oacc[0][jd] = __builtin_amdgcn_mfma_f32_16x16x32_bf16(aP0, bV, oacc[0][jd], 0, 0, 0);
                oacc[1][jd] = __builtin_amdgcn_mfma_f32_16x16x32_bf16(aP1, bV, oacc[1][jd], 0, 0, 0);
            }
        }

        __syncthreads();   // LDS readers drained (+ drains vmcnt -> regs valid)
        // refill Ksu/Vtu from registers (UNCONDITIONAL; dead on last iter)
        #pragma unroll
        for (int i = 0; i < 6; ++i)
            *(bfrag*)(Ksu + (wave + 4 * i) * 512 + lane * 8) = kreg[i];
        #pragma unroll
        for (int i = 0; i < 4; ++i)
            *(bfrag*)(Vtu + (wave + 4 * i) * 512 + lane * 8) = vreg[i];
        __syncthreads();   // new tile visible before next QK^T
    }

    // reduce l partials, epilogue
    #pragma unroll
    for (int sp = 0; sp < 2; ++sp) {
        #pragma unroll
        for (int r = 0; r < 4; ++r) {
            float v = lp[sp][r];
            #pragma unroll
            for (int msk = 1; msk < 16; msk <<= 1) v += __shfl_xor(v, msk);
            const float inv = 1.f / v;
            ushort* op = o + (size_t)(b * SS + q0 + sp * 64 + wstrip + quad * 4 + r)
                             * (HH * DV) + h * DV;
            #pragma unroll
            for (int jd = 0; jd < 8; ++jd)
                op[jd * 16 + n] = f2bf(oacc[sp][jd][r] * inv);
        }
    }
}

// ---------------- launch ----------------
extern "C" void kernel_launch(void* const* d_in, const int* in_sizes, int n_in,
                              void* d_out, int out_size, void* d_ws, size_t ws_size,
                              hipStream_t stream) {
    const float* hs    = (const float*)d_in[0];
    const float* cosb  = (const float*)d_in[1];
    const float* sinb  = (const float*)d_in[2];
    const float* Wqa   = (const float*)d_in[3];
    const float* qa_w  = (const float*)d_in[4];
    const float* Wqb   = (const float*)d_in[5];
    const float* Wkva  = (const float*)d_in[6];
    const float* kva_w = (const float*)d_in[7];
    const float* Wkvb  = (const float*)d_in[8];
    const float* Wo    = (const float*)d_in[9];
    float* out = (float*)d_out;

    const int T = BB * SS; // 4096 tokens

    char* w = (char*)d_ws;
    auto alloc = [&](size_t bytes) {
        void* r = (void*)w;
        w += (bytes + 255) & ~(size_t)255;
        return r;
    };
    ushort* hs_bf  = (ushort*)alloc((size_t)T * DD * 2);            // 16.8 MB
    ushort* Wcat   = (ushort*)alloc((size_t)NCATP * DD * 2);        //  9.4
    ushort* Wqbt   = (ushort*)alloc((size_t)(HH * DQ) * QL * 2);    //  9.4
    ushort* Wkvbt  = (ushort*)alloc((size_t)(HH * KVD) * KVL * 2);  //  4.2
    ushort* Wot    = (ushort*)alloc((size_t)DD * DD * 2);           //  8.4
    ushort* qa_bf  = (ushort*)alloc((size_t)T * QL * 2);            // 12.6
    ushort* Qbuf   = (ushort*)alloc((size_t)T * HH * DQ * 2);       // 25.2
    ushort* ckv_bf = (ushort*)alloc((size_t)T * CKVS * 2);          //  5.2
    ushort* kvn_bf = (ushort*)alloc((size_t)T * KVL * 2);           //  4.2
    ushort* kv_bf  = (ushort*)alloc((size_t)T * HH * KVD * 2);      // 33.6
    ushort* krb    = (ushort*)alloc((size_t)T * DR * 2);            //  0.5
    // aliases (lifetimes verified):
    ushort* Vtb    = Wcat;   // over Wcat+Wqbt (dead after gemmAW/gemmQKV)
    ushort* ao_bf  = hs_bf;  // hs_bf dead after gemmAW

    // 0. cast hs + transpose Wqa/Wkva in ONE launch (both feed gemmAW)
    WtBatch wb;
    wb.src[0] = Wqa;  wb.dst[0] = Wcat;                   wb.K[0] = DD; wb.N[0] = QL;       wb.nx[0] = 48;
    wb.src[1] = Wkva; wb.dst[1] = Wcat + (size_t)QL * DD; wb.K[1] = DD; wb.N[1] = KVL + DR; wb.nx[1] = 20;
    wb.base[0] = 0;
    wb.base[1] = wb.nx[0] * (DD / 32);                // 3072
    wb.base[2] = wb.base[1] + wb.nx[1] * (DD / 32);   // 4352
    castw<<<8192 + 4352, 256, 0, stream>>>(hs, hs_bf, wb);

    // 1. gemmA (144 blocks) + Wqb/Wkvb/Wo transpose walkers (112 blocks)
    gemmAW<<<dim3(256), 512, 0, stream>>>(hs_bf, Wcat, qa_bf, ckv_bf,
                                          Wqb, Wqbt, Wkvb, Wkvbt, Wo, Wot);
    // 2. both RMSNorms (qa in-place; ckv->kvn + k_rot rope) in ONE launch
    rmsnorm2<<<2 * T, 256, 0, stream>>>(qa_bf, qa_w, ckv_bf, kva_w, kvn_bf,
                                        krb, cosb, sinb);
    // 3. grouped GEMM (8-phase 256^2): Q (192 blocks) + kv (256 blocks)
    gemmQKV<<<dim3(448), 512, 0, stream>>>(qa_bf, Wqbt, Qbuf,
                                           kvn_bf, Wkvbt, kv_bf);
    // 4. rope Q + V transpose in ONE launch
    ropevprep<<<T + 8192, 256, 0, stream>>>(Qbuf, cosb, sinb, kv_bf, Vtb);
    // 5. MFMA flash attention (4-wave, 2-strip; r7-verified) -> ao (bf16)
    fattn_mfma<<<dim3(16, HH, BB), 256, 0, stream>>>(Qbuf, kv_bf, krb, Vtb, ao_bf);
    // 6. out = ao @ Wo (fp32), 256x128 tile -> 256 blocks (full fill)
    gemmW<DD, 16, DD><<<dim3(256), 512, 0, stream>>>(ao_bf, Wot, out);
}